// Round 11
// baseline (214.825 us; speedup 1.0000x reference)
//
#include <hip/hip_runtime.h>
#include <stdint.h>

#define B_SZ 4096
#define D_SZ 512
#define SHIFT 64.0f

typedef __attribute__((ext_vector_type(4))) float floatx4;
typedef __attribute__((ext_vector_type(2))) long lng2;
typedef unsigned char u8;
typedef unsigned int u32;

#define GLD_LDS16(gp, sp)                                                              \
    __builtin_amdgcn_global_load_lds(                                                  \
        (const __attribute__((address_space(1))) void*)(gp),                           \
        (__attribute__((address_space(3))) void*)(sp), 16, 0, 0)

#define FP8MFMA(accv, av, bv)                                                          \
    accv = __builtin_amdgcn_mfma_f32_16x16x32_fp8_fp8(av, bv, accv, 0, 0, 0)

// ---- K1: fp32->fp8(e4m3) convert (K-interleaved layout) + per-row time,
//      fused: histogram (block 0), accumulator zeroing, entailment partials.
//      K-perm: within each 64B K-window, 8B group (h,c) -> slot c*2+h; applied
//      to BOTH operands => Grammian unchanged. ----
__global__ __launch_bounds__(256) void prep_kernel(
    const float* __restrict__ img, const float* __restrict__ dna,
    const float* __restrict__ txt, const float* __restrict__ curv_p,
    const int* __restrict__ labels, int* __restrict__ hist,
    u8* __restrict__ f8, float* __restrict__ times,
    float* __restrict__ zero_f, float* __restrict__ ent_partial) {
    __shared__ int lhist[512];
    __shared__ float red[4];
    int t = threadIdx.x;
    int gid = blockIdx.x * 256 + t;
    if (gid < 49155) zero_f[gid] = 0.0f;    // rsum/csum + ce_acc/ent_acc/done

    if (blockIdx.x == 0) {                  // label histogram, single block
        lhist[t] = 0; lhist[t + 256] = 0;
        __syncthreads();
        for (int n = t; n < B_SZ; n += 256) atomicAdd(&lhist[labels[n]], 1);
        __syncthreads();
        hist[t] = lhist[t]; hist[t + 256] = lhist[t + 256];
    }

    int wave = gid >> 6;  // 0..12287
    int lane = t & 63;
    const float* src = (wave < B_SZ) ? img : (wave < 2 * B_SZ) ? dna : txt;
    int row = wave & (B_SZ - 1);
    const float* p = src + row * D_SZ + lane * 8;
    float4 v0 = *(const float4*)(p);
    float4 v1 = *(const float4*)(p + 4);
    float ss = v0.x*v0.x + v0.y*v0.y + v0.z*v0.z + v0.w*v0.w
             + v1.x*v1.x + v1.y*v1.y + v1.z*v1.z + v1.w*v1.w;
    u32 w0 = __builtin_amdgcn_cvt_pk_fp8_f32(v0.x, v0.y, 0, false);
    w0 = __builtin_amdgcn_cvt_pk_fp8_f32(v0.z, v0.w, w0, true);
    u32 w1 = __builtin_amdgcn_cvt_pk_fp8_f32(v1.x, v1.y, 0, false);
    w1 = __builtin_amdgcn_cvt_pk_fp8_f32(v1.z, v1.w, w1, true);
    uint2 pk; pk.x = w0; pk.y = w1;
    // lane = 8B group: window lane>>3, half (lane>>2)&1, chunk lane&3
    int gperm = (lane & 56) | ((lane & 3) << 1) | ((lane >> 2) & 1);
    *(uint2*)(f8 + (size_t)wave * D_SZ + gperm * 8) = pk;

    bool isdna = (wave >= B_SZ) && (wave < 2 * B_SZ);
    float dot = 0.0f, ssy = 0.0f;
    if (isdna) {                            // matching image row for entailment
        const float* y = img + row * D_SZ + lane * 8;
        float4 y0 = *(const float4*)y, y1 = *(const float4*)(y + 4);
        dot = v0.x*y0.x + v0.y*y0.y + v0.z*y0.z + v0.w*y0.w
            + v1.x*y1.x + v1.y*y1.y + v1.z*y1.z + v1.w*y1.w;
        ssy = y0.x*y0.x + y0.y*y0.y + y0.z*y0.z + y0.w*y0.w
            + y1.x*y1.x + y1.y*y1.y + y1.z*y1.z + y1.w*y1.w;
    }
    #pragma unroll
    for (int m = 1; m < 64; m <<= 1) {
        ss += __shfl_xor(ss, m);
        if (isdna) { dot += __shfl_xor(dot, m); ssy += __shfl_xor(ssy, m); }
    }
    float curv = curv_p[0];
    float ep = 0.0f;
    if (lane == 0) {
        float xt = sqrtf(1.0f / curv + ss);
        times[wave] = xt;
        if (isdna) {
            float yt = sqrtf(1.0f / curv + ssy);
            float nx = sqrtf(ss);
            float c = curv * (dot - xt * yt);                      // <= -1
            float numer = yt + c * xt;
            float denom = nx * sqrtf(fmaxf(c * c - 1.0f, 0.0f));
            float ai = numer / (denom + 1e-8f);
            ai = fminf(fmaxf(ai, -1.0f + 1e-8f), 1.0f - 1e-8f);
            float ang = acosf(ai);
            float as_in = 0.2f / (nx * sqrtf(curv) + 1e-6f);       // 2*min_radius
            as_in = fminf(fmaxf(as_in, -1.0f + 1e-6f), 1.0f - 1e-6f);
            float ap = asinf(as_in);
            ep = fmaxf(ang - ap, 0.0f);
        }
    }
    if (blockIdx.x >= 1024 && blockIdx.x < 2048) {   // pure-dna blocks
        if (lane == 0) red[t >> 6] = ep;
        __syncthreads();
        if (t == 0) ent_partial[blockIdx.x - 1024] = red[0] + red[1] + red[2] + red[3];
    }
}

// ---- K2: batched fp8 MFMA GEMM (A·B^T), R28: 256x256 tile, 512 thr =
//      8 waves, 128x64 patch/wave (wr=wave>>2, wc=wave&3), acc[8][4].
//      = R19 geometry (correctness-verified: absmax 0.0) x R24 schedule
//      (the only proven winner: counted-vmcnt dist-2, 1 barrier/K-step,
//      no setprio) x __launch_bounds__(512,1).
//      Why: all 128-class schedules plateau 88-95us; binding cost = barrier+
//      ds_read per MFMA. 256^2 gives 64 MFMA/wave/barrier (2x), 0.19
//      ds_read/MFMA (vs 0.25), half the staging volume, half the barriers.
//      R19 failed ONLY via spill: plain launch_bounds(512) pins a 128-VGPR
//      budget; acc[8][4]=128 + frags overflowed -> 43MB scratch. (512,1)
//      raises the budget to ~512 (m08: no spill through 450); acc 128 +
//      frags 24 + addr ~50 fits. Cost: 96KB LDS -> 1 block/CU, 2 waves/SIMD
//      -- acceptable because counted vmcnt keeps stages in flight across
//      barriers (what R17's 1-block/CU config lacked).
//      VALIDITY CHECK next round: WRITE_SIZE must stay ~26-31MB. If it
//      balloons, the budget spilled and this result is void -> revert R24.
//      vmcnt ledger (4 GLD/thread/stage: A0,A1,B0,B1): loop top in-flight =
//      stage(si)+stage(si+1) = 8; await stage(si) -> vmcnt(4); si=7 ->
//      vmcnt(0). Buffer safety: stage(si+2) -> buf[(si+2)%3] = buf[(si-1)%3],
//      whose ds_reads completed before barrier(si) (lgkmcnt(0) pre-barrier).
//      Ledger: R27 64x64/wave@256thr = 93 (VGPR 128 -> occ 19.7%). R26
//      reg-dbuf spill 93. R25 dist-3+setprio 97. R24 = 88.5 (win). R23 XCD
//      remap regressed. R22 direct-L2 168. R20 4-phase +10%. R15 threadfence
//      storm. Non-gemm ~75us constant.
__global__ __launch_bounds__(512, 1) void gemm_epi_kernel(
    const u8* __restrict__ f8, const float* __restrict__ times,
    const int* __restrict__ labels,
    const float* __restrict__ ls_p, const float* __restrict__ curv_p,
    float* __restrict__ rsum_e, float* __restrict__ rsum_t,
    float* __restrict__ csum_e, float* __restrict__ csum_t) {
    __shared__ u8 sA[3][256 * 64];    // 48 KB
    __shared__ u8 sB[3][256 * 64];    // 48 KB -> 96 KB total, 1 block/CU

    int z = blockIdx.z;                   // 0:(img,dna) 1:(img,txt) 2:(dna,txt)
    int pa = (z == 2) ? 1 : 0;
    int pb = (z == 0) ? 1 : 2;
    const u8* A  = f8 + (size_t)pa * (B_SZ * D_SZ);
    const u8* Bm = f8 + (size_t)pb * (B_SZ * D_SZ);

    int t = threadIdx.x;
    int rowBlk = blockIdx.y * 256;
    int colBlk = blockIdx.x * 256;
    int wave = t >> 6, lane = t & 63;
    int wr = wave >> 2;                   // row 128-group (0..1)
    int wc = wave & 3;                    // col 64-group (0..3)

    // Staging (R19-verified): wave w, issue i covers 16 rows starting at
    // w*32 + i*16; lane l -> row l>>2, chunk (l&3)^((l>>3)&3). LDS holds
    // chunk slot^((row>>1)&3) (involution; frag read applies the same XOR).
    int chunk = (lane & 3) ^ ((lane >> 3) & 3);
    const u8* gA0 = A  + (size_t)(rowBlk + wave * 32 + (lane >> 2)) * D_SZ + chunk * 16;
    const u8* gA1 = gA0 + 16 * D_SZ;
    const u8* gB0 = Bm + (size_t)(colBlk + wave * 32 + (lane >> 2)) * D_SZ + chunk * 16;
    const u8* gB1 = gB0 + 16 * D_SZ;

    int q = lane >> 4, s = lane & 15;
    // frag-read swizzle slot: q ^ ((row>>1)&3) == q ^ ((s>>1)&3) since all
    // row bases (wr*128, wc*64, ii*16, j*16) are 16-aligned.
    int slot16 = (q ^ ((s >> 1) & 3)) << 4;
    int aBase = (wr * 128 + s) * 64 + slot16;    // + ii*1024 per fragment
    int bBase = (wc * 64  + s) * 64 + slot16;    // + j*1024 per fragment

    floatx4 acc[8][4];
    #pragma unroll
    for (int ii = 0; ii < 8; ++ii)
        #pragma unroll
        for (int j = 0; j < 4; ++j) acc[ii][j] = (floatx4){0.f, 0.f, 0.f, 0.f};

    {   // prologue: stage K-steps 0,1 into buffers 0,1 (8 loads in flight;
        // per-stage issue order A0,A1,B0,B1 so "oldest 4" == one stage).
        GLD_LDS16(gA0,      &sA[0][wave * 2048]);
        GLD_LDS16(gA1,      &sA[0][wave * 2048 + 1024]);
        GLD_LDS16(gB0,      &sB[0][wave * 2048]);
        GLD_LDS16(gB1,      &sB[0][wave * 2048 + 1024]);
        GLD_LDS16(gA0 + 64, &sA[1][wave * 2048]);
        GLD_LDS16(gA1 + 64, &sA[1][wave * 2048 + 1024]);
        GLD_LDS16(gB0 + 64, &sB[1][wave * 2048]);
        GLD_LDS16(gB1 + 64, &sB[1][wave * 2048 + 1024]);
    }

    #pragma unroll
    for (int si = 0; si < D_SZ / 64; ++si) {
        const int cur = si % 3;
        // own prior-step ds_reads consumed before the barrier (buffer-reuse
        // safety for the distance-2 DMA target); then wait ONLY stage(si).
        asm volatile("s_waitcnt lgkmcnt(0)" ::: "memory");
        if (si < 7) { asm volatile("s_waitcnt vmcnt(4)" ::: "memory"); }
        else        { asm volatile("s_waitcnt vmcnt(0)" ::: "memory"); }
        asm volatile("s_barrier" ::: "memory");
        // prefetch distance 2: stage(si+2) into buf[(si+2)%3] (= buf[(si-1)%3],
        // fully read before barrier(si)). Loads stay in flight across the
        // next barrier -- no drain anywhere in the loop.
        if (si < 6) {
            const int nxb = (si + 2) % 3;
            const int ko  = (si + 2) * 64;
            GLD_LDS16(gA0 + ko, &sA[nxb][wave * 2048]);
            GLD_LDS16(gA1 + ko, &sA[nxb][wave * 2048 + 1024]);
            GLD_LDS16(gB0 + ko, &sB[nxb][wave * 2048]);
            GLD_LDS16(gB1 + ko, &sB[nxb][wave * 2048 + 1024]);
        }
        const u8* pA = &sA[cur][0];
        const u8* pB = &sB[cur][0];
        lng2 b0 = *(const lng2*)(pB + bBase);
        lng2 b1 = *(const lng2*)(pB + bBase + 1024);
        lng2 b2 = *(const lng2*)(pB + bBase + 2048);
        lng2 b3 = *(const lng2*)(pB + bBase + 3072);
        #pragma unroll
        for (int ii = 0; ii < 8; ++ii) {
            lng2 a = *(const lng2*)(pA + aBase + ii * 1024);
            FP8MFMA(acc[ii][0], a.x, b0.x); FP8MFMA(acc[ii][1], a.x, b1.x);
            FP8MFMA(acc[ii][2], a.x, b2.x); FP8MFMA(acc[ii][3], a.x, b3.x);
            FP8MFMA(acc[ii][0], a.y, b0.y); FP8MFMA(acc[ii][1], a.y, b1.y);
            FP8MFMA(acc[ii][2], a.y, b2.y); FP8MFMA(acc[ii][3], a.y, b3.y);
        }
    }

    // ---- slim fused epilogue (verified R7-R27; R19 ii<8 form) ----
    float ls = ls_p[0];
    float curv = curv_p[0];
    float rsc = rsqrtf(curv);
    float c2 = -ls * rsc;
    float c1 = c2 * 0.69314718f;
    float sh2p = SHIFT * 1.44269504f + c2;
    const float* tA = times + pa * B_SZ;
    const float* tB = times + pb * B_SZ;

    int rowbase = rowBlk + wr * 128;
    int colbase = colBlk + wc * 64;

    float tb[4]; int lb[4]; int mcol[4];
    #pragma unroll
    for (int j = 0; j < 4; ++j) {
        mcol[j] = colbase + j * 16 + s;
        tb[j] = tB[mcol[j]];
        lb[j] = labels[mcol[j]];
    }
    float colE[4] = {0.f, 0.f, 0.f, 0.f}, colT[4] = {0.f, 0.f, 0.f, 0.f};

    float* rsE = rsum_e + z * B_SZ;
    float* rsT = rsum_t + z * B_SZ;
    float* csE = csum_e + z * B_SZ;
    float* csT = csum_t + z * B_SZ;

    #pragma unroll
    for (int ii = 0; ii < 8; ++ii) {
        int nb = rowbase + ii * 16 + q * 4;   // this lane's 4 C rows
        float cta[4]; int la[4];
        #pragma unroll
        for (int r = 0; r < 4; ++r) { cta[r] = curv * tA[nb + r]; la[r] = labels[nb + r]; }
        float re[4] = {0.f, 0.f, 0.f, 0.f}, rt[4] = {0.f, 0.f, 0.f, 0.f};
        #pragma unroll
        for (int j = 0; j < 4; ++j) {
            floatx4 a = acc[ii][j];
            #pragma unroll
            for (int r = 0; r < 4; ++r) {
                float zc = fmaf(-curv, a[r], cta[r] * tb[j]);
                zc = fmaxf(zc, 1.0f + 1e-8f);
                float lz = __log2f(zc);
                float e = __builtin_amdgcn_exp2f(fmaf(c2, lz, sh2p));
                float tl2 = (la[r] == lb[j]) ? fmaf(c1, lz, c1) : 0.0f;
                re[r] += e; rt[r] += tl2;
                colE[j] += e; colT[j] += tl2;
            }
        }
        #pragma unroll
        for (int r = 0; r < 4; ++r) {
            #pragma unroll
            for (int m = 1; m <= 8; m <<= 1) {
                re[r] += __shfl_xor(re[r], m);
                rt[r] += __shfl_xor(rt[r], m);
            }
        }
        #pragma unroll
        for (int r = 0; r < 4; ++r) {
            if (s == r) {
                atomicAdd(&rsE[nb + r], re[r]);
                atomicAdd(&rsT[nb + r], rt[r]);
            }
        }
    }
    #pragma unroll
    for (int j = 0; j < 4; ++j) {
        colE[j] += __shfl_xor(colE[j], 16); colE[j] += __shfl_xor(colE[j], 32);
        colT[j] += __shfl_xor(colT[j], 16); colT[j] += __shfl_xor(colT[j], 32);
        if (q == 0) {
            atomicAdd(&csE[mcol[j]], colE[j]);
            atomicAdd(&csT[mcol[j]], colT[j]);
        }
    }
}

// ---- parallel finalize: 16 blocks, device-scope atomic accumulation; last
//      block (done counter) writes out. atomicAdd(p,0) read avoids stale L2. ----
__global__ __launch_bounds__(256) void finalize_kernel(
    const float* __restrict__ rsum_e, const float* __restrict__ rsum_t,
    const float* __restrict__ csum_e, const float* __restrict__ csum_t,
    const int* __restrict__ labels, const int* __restrict__ hist,
    const float* __restrict__ ent_partial,
    float* __restrict__ ce_acc, float* __restrict__ ent_acc,
    int* __restrict__ done, float* __restrict__ out) {
    __shared__ float red[4], red2[4];
    int b = blockIdx.x, tid = threadIdx.x;
    int n = b * 256 + tid;                 // covers 0..4095 exactly
    float Sn = (float)hist[labels[n]];
    float part = 0.0f;
    #pragma unroll
    for (int p = 0; p < 3; ++p) {
        part += Sn * (__logf(rsum_e[p * B_SZ + n]) - SHIFT) - rsum_t[p * B_SZ + n];
        part += Sn * (__logf(csum_e[p * B_SZ + n]) - SHIFT) - csum_t[p * B_SZ + n];
    }
    float ep = (b < 4) ? ent_partial[b * 256 + tid] : 0.0f;
    #pragma unroll
    for (int m = 1; m < 64; m <<= 1) {
        part += __shfl_xor(part, m);
        ep   += __shfl_xor(ep, m);
    }
    if ((tid & 63) == 0) { red[tid >> 6] = part; red2[tid >> 6] = ep; }
    __syncthreads();
    if (tid == 0) {
        atomicAdd(ce_acc, red[0] + red[1] + red[2] + red[3]);
        atomicAdd(ent_acc, red2[0] + red2[1] + red2[2] + red2[3]);
        __threadfence();
        if (atomicAdd(done, 1) == 15) {        // last of 16 blocks
            float ce = atomicAdd(ce_acc, 0.0f);    // coherent read
            float ent = atomicAdd(ent_acc, 0.0f);
            float contr = ce / (6.0f * (float)B_SZ);
            ent /= (float)B_SZ;
            out[0] = contr + 0.2f * ent;
            out[1] = contr;
            out[2] = ent;
        }
    }
}

// ---- workspace layout (bytes) ----
//   0       : fp8 feats (K-interleaved), 3*4096*512 = 6,291,456
//   6291456 : times[3][4096] f32   (49,152)
//   6340608 : rsum_e[12288 f]  \
//   6389760 : rsum_t           | zero region: 49155 floats
//   6438912 : csum_e           | (incl. ce_acc, ent_acc, done)
//   6488064 : csum_t           |
//   6537216 : ce_acc f32; 6537220: ent_acc f32; 6537224: done i32
//   6537228 : ent_partial[1024] f32 (every slot written by its dna block)
//   6541324 : hist[512] int (fully written by prep block 0)
extern "C" void kernel_launch(void* const* d_in, const int* in_sizes, int n_in,
                              void* d_out, int out_size, void* d_ws, size_t ws_size,
                              hipStream_t stream) {
    const float* img    = (const float*)d_in[0];
    const float* dna    = (const float*)d_in[1];
    const float* txt    = (const float*)d_in[2];
    const int*   labels = (const int*)d_in[3];
    const float* ls     = (const float*)d_in[4];
    const float* curv   = (const float*)d_in[5];

    char* ws = (char*)d_ws;
    u8*    f8     = (u8*)ws;
    float* times  = (float*)(ws + 6291456);
    float* rsum_e = (float*)(ws + 6340608);
    float* rsum_t = (float*)(ws + 6389760);
    float* csum_e = (float*)(ws + 6438912);
    float* csum_t = (float*)(ws + 6488064);
    float* ce_acc = (float*)(ws + 6537216);
    float* ent_acc= (float*)(ws + 6537220);
    int*   done   = (int*)  (ws + 6537224);
    float* ent_p  = (float*)(ws + 6537228);
    int*   hist   = (int*)  (ws + 6541324);

    prep_kernel<<<3072, 256, 0, stream>>>(img, dna, txt, curv, labels, hist,
                                          f8, times, rsum_e, ent_p);
    dim3 g(16, 16, 3);
    gemm_epi_kernel<<<g, 512, 0, stream>>>(f8, times, labels, ls, curv,
                                           rsum_e, rsum_t, csum_e, csum_t);
    finalize_kernel<<<16, 256, 0, stream>>>(rsum_e, rsum_t, csum_e, csum_t,
                                            labels, hist, ent_p,
                                            ce_acc, ent_acc, done, (float*)d_out);
}

// Round 13
// 149.965 us; speedup vs baseline: 1.4325x; 1.4325x over previous
//
#include <hip/hip_runtime.h>
#include <stdint.h>

#define B_SZ 4096
#define D_SZ 512
#define SHIFT 64.0f

typedef __attribute__((ext_vector_type(4))) float floatx4;
typedef __attribute__((ext_vector_type(2))) long lng2;
typedef unsigned char u8;
typedef unsigned int u32;

#define GLD_LDS16(gp, sp)                                                              \
    __builtin_amdgcn_global_load_lds(                                                  \
        (const __attribute__((address_space(1))) void*)(gp),                           \
        (__attribute__((address_space(3))) void*)(sp), 16, 0, 0)

#define FP8MFMA(accv, av, bv)                                                          \
    accv = __builtin_amdgcn_mfma_f32_16x16x32_fp8_fp8(av, bv, accv, 0, 0, 0)

// ---- K1: fp32->fp8(e4m3) convert (K-interleaved layout) + per-row time,
//      fused: histogram (block 0), accumulator zeroing, entailment partials.
//      K-perm: within each 64B K-window, 8B group (h,c) -> slot c*2+h; applied
//      to BOTH operands => Grammian unchanged. ----
__global__ __launch_bounds__(256) void prep_kernel(
    const float* __restrict__ img, const float* __restrict__ dna,
    const float* __restrict__ txt, const float* __restrict__ curv_p,
    const int* __restrict__ labels, int* __restrict__ hist,
    u8* __restrict__ f8, float* __restrict__ times,
    float* __restrict__ zero_f, float* __restrict__ ent_partial) {
    __shared__ int lhist[512];
    __shared__ float red[4];
    int t = threadIdx.x;
    int gid = blockIdx.x * 256 + t;
    if (gid < 49155) zero_f[gid] = 0.0f;    // rsum/csum + ce_acc/ent_acc/done

    if (blockIdx.x == 0) {                  // label histogram, single block
        lhist[t] = 0; lhist[t + 256] = 0;
        __syncthreads();
        for (int n = t; n < B_SZ; n += 256) atomicAdd(&lhist[labels[n]], 1);
        __syncthreads();
        hist[t] = lhist[t]; hist[t + 256] = lhist[t + 256];
    }

    int wave = gid >> 6;  // 0..12287
    int lane = t & 63;
    const float* src = (wave < B_SZ) ? img : (wave < 2 * B_SZ) ? dna : txt;
    int row = wave & (B_SZ - 1);
    const float* p = src + row * D_SZ + lane * 8;
    float4 v0 = *(const float4*)(p);
    float4 v1 = *(const float4*)(p + 4);
    float ss = v0.x*v0.x + v0.y*v0.y + v0.z*v0.z + v0.w*v0.w
             + v1.x*v1.x + v1.y*v1.y + v1.z*v1.z + v1.w*v1.w;
    u32 w0 = __builtin_amdgcn_cvt_pk_fp8_f32(v0.x, v0.y, 0, false);
    w0 = __builtin_amdgcn_cvt_pk_fp8_f32(v0.z, v0.w, w0, true);
    u32 w1 = __builtin_amdgcn_cvt_pk_fp8_f32(v1.x, v1.y, 0, false);
    w1 = __builtin_amdgcn_cvt_pk_fp8_f32(v1.z, v1.w, w1, true);
    uint2 pk; pk.x = w0; pk.y = w1;
    // lane = 8B group: window lane>>3, half (lane>>2)&1, chunk lane&3
    int gperm = (lane & 56) | ((lane & 3) << 1) | ((lane >> 2) & 1);
    *(uint2*)(f8 + (size_t)wave * D_SZ + gperm * 8) = pk;

    bool isdna = (wave >= B_SZ) && (wave < 2 * B_SZ);
    float dot = 0.0f, ssy = 0.0f;
    if (isdna) {                            // matching image row for entailment
        const float* y = img + row * D_SZ + lane * 8;
        float4 y0 = *(const float4*)y, y1 = *(const float4*)(y + 4);
        dot = v0.x*y0.x + v0.y*y0.y + v0.z*y0.z + v0.w*y0.w
            + v1.x*y1.x + v1.y*y1.y + v1.z*y1.z + v1.w*y1.w;
        ssy = y0.x*y0.x + y0.y*y0.y + y0.z*y0.z + y0.w*y0.w
            + y1.x*y1.x + y1.y*y1.y + y1.z*y1.z + y1.w*y1.w;
    }
    #pragma unroll
    for (int m = 1; m < 64; m <<= 1) {
        ss += __shfl_xor(ss, m);
        if (isdna) { dot += __shfl_xor(dot, m); ssy += __shfl_xor(ssy, m); }
    }
    float curv = curv_p[0];
    float ep = 0.0f;
    if (lane == 0) {
        float xt = sqrtf(1.0f / curv + ss);
        times[wave] = xt;
        if (isdna) {
            float yt = sqrtf(1.0f / curv + ssy);
            float nx = sqrtf(ss);
            float c = curv * (dot - xt * yt);                      // <= -1
            float numer = yt + c * xt;
            float denom = nx * sqrtf(fmaxf(c * c - 1.0f, 0.0f));
            float ai = numer / (denom + 1e-8f);
            ai = fminf(fmaxf(ai, -1.0f + 1e-8f), 1.0f - 1e-8f);
            float ang = acosf(ai);
            float as_in = 0.2f / (nx * sqrtf(curv) + 1e-6f);       // 2*min_radius
            as_in = fminf(fmaxf(as_in, -1.0f + 1e-6f), 1.0f - 1e-6f);
            float ap = asinf(as_in);
            ep = fmaxf(ang - ap, 0.0f);
        }
    }
    if (blockIdx.x >= 1024 && blockIdx.x < 2048) {   // pure-dna blocks
        if (lane == 0) red[t >> 6] = ep;
        __syncthreads();
        if (t == 0) ent_partial[blockIdx.x - 1024] = red[0] + red[1] + red[2] + red[3];
    }
}

// ---- K2: batched fp8 MFMA GEMM (A·B^T), 128x128 tile, 8 waves, 32x64/wave.
//      R30 = R29 persistent 6-tile kernel with the vmcnt LEDGER BUG fixed.
//      R29 failed (absmax 468) because it kept vmcnt(4) from R27's
//      4-loads/stage geometry; this kernel stages 2 loads/stage (1 gA + 1
//      gB), so in-flight at each K-step top = stage(si)+stage(si+1) = 4 and
//      the correct counted wait is vmcnt(2) -- vmcnt(4) waited for NOTHING
//      and frag reads raced the DMA. R24 (the 88.5us champion schedule)
//      used vmcnt(2); one-token transcription error.
//      Structure (unchanged from R29): 512 blocks (exact 2/CU residency),
//      6 consecutive linear tiles each; R24 in-tile schedule (counted-vmcnt
//      dist-2, 1 barrier/K-step, no setprio); cross-tile pipelining:
//        * next tile's stage(0) issued at si==7 post-barrier (buf0 last
//          read si==6; all waves past barrier(7) -> safe).
//        * next tile's stage(1) post-loop after lgkmcnt(0)+barrier (buf1
//          read at si==7 by all waves -> safe).
//        * epilogue runs with 4 staging loads in flight -> next prologue
//          hidden. Epilogue's own loads/atomics also count vmcnt, so next
//          tile's vmcnt(2) is conservative-correct (over-waits slightly).
//      vmcnt ledger (2 GLD/stage): si in [0,6] top: in-flight 4 ->
//      vmcnt(2) awaits stage(si); si==7: in-flight = stage(7) -> vmcnt(0).
//      Buffer reuse at tile boundary: stage2->buf2 (last read prev si==5),
//      stage3->buf0 (read si==0) -- both behind lgkmcnt(0)+barrier. Safe.
//      Ledger: R28/R19 256^2 -> allocator pins 128 VGPR at 512thr -> spill
//      (dead). R27 64x64/wave@256thr VGPR 128 -> occ 19.7%, 93. R26
//      reg-dbuf spill 93. R25 dist-3+setprio 97. R24 = 88.5 (champion).
//      R23 XCD remap regressed. R22 direct-L2 168. R20 4-phase +10%.
//      R15 threadfence storm. Non-gemm ~75us constant.
__global__ __launch_bounds__(512, 4) void gemm_epi_kernel(
    const u8* __restrict__ f8, const float* __restrict__ times,
    const int* __restrict__ labels,
    const float* __restrict__ ls_p, const float* __restrict__ curv_p,
    float* __restrict__ rsum_e, float* __restrict__ rsum_t,
    float* __restrict__ csum_e, float* __restrict__ csum_t) {
    __shared__ u8 sA[3][128 * 64];    // 24 KB
    __shared__ u8 sB[3][128 * 64];    // 24 KB -> 48 KB total, 2 blocks/CU

    int t = threadIdx.x;
    int wave = t >> 6, lane = t & 63;
    int wr = wave >> 1;                   // row 32-group (0..3)
    int wc = wave & 1;                    // col 64-group (0..1)
    int chunk = (t & 3) ^ ((t >> 3) & 3);
    int q = lane >> 4, s = lane & 15;
    int slot16 = (q ^ ((s >> 1) & 3)) << 4;
    int aBase = (wr * 32 + s) * 64 + slot16;     // + ii*1024 per fragment
    int bBase = (wc * 64 + s) * 64 + slot16;     // + j*1024 per fragment

    float ls = ls_p[0];
    float curv = curv_p[0];
    float rsc = rsqrtf(curv);
    float c2 = -ls * rsc;
    float c1 = c2 * 0.69314718f;
    float sh2p = SHIFT * 1.44269504f + c2;

    const u8* gA = nullptr;  const u8* gB = nullptr;

    #pragma unroll 1
    for (int tile = 0; tile < 6; ++tile) {
        int tl  = blockIdx.x * 6 + tile;          // 0..3071
        int z   = tl >> 10;                       // 0:(img,dna) 1:(img,txt) 2:(dna,txt)
        int rem = tl & 1023;
        int rowBlk = (rem >> 5) * 128;
        int colBlk = (rem & 31) * 128;
        int pa = (z == 2) ? 1 : 0;
        int pb = (z == 0) ? 1 : 2;
        const u8* A  = f8 + (size_t)pa * (B_SZ * D_SZ);
        const u8* Bm = f8 + (size_t)pb * (B_SZ * D_SZ);
        // Staging ptrs (R21/R24-verified mapping): thread t -> row t>>2,
        // global chunk (t&3)^((t>>3)&3); LDS linear => involution swizzle.
        const u8* gA_n = A  + (size_t)(rowBlk + (t >> 2)) * D_SZ + chunk * 16;
        const u8* gB_n = Bm + (size_t)(colBlk + (t >> 2)) * D_SZ + chunk * 16;

        if (tile == 0) {
            // cold prologue: stage K-steps 0,1 into buffers 0,1
            GLD_LDS16(gA_n,      &sA[0][wave * 1024]);
            GLD_LDS16(gB_n,      &sB[0][wave * 1024]);
            GLD_LDS16(gA_n + 64, &sA[1][wave * 1024]);
            GLD_LDS16(gB_n + 64, &sB[1][wave * 1024]);
        }
        // (for tile>0, stage(0)/stage(1) were issued during the previous
        //  tile's si==7 body and pre-epilogue, using gAx/gBx)
        gA = gA_n; gB = gB_n;

        floatx4 acc[2][4];
        #pragma unroll
        for (int ii = 0; ii < 2; ++ii)
            #pragma unroll
            for (int j = 0; j < 4; ++j) acc[ii][j] = (floatx4){0.f, 0.f, 0.f, 0.f};

        // next-tile staging ptrs (used only when tile<5)
        int tln  = tl + 1;
        int zn   = tln >> 10;
        int remn = tln & 1023;
        const u8* An  = f8 + (size_t)((zn == 2) ? 1 : 0) * (B_SZ * D_SZ);
        const u8* Bn  = f8 + (size_t)((zn == 0) ? 1 : 2) * (B_SZ * D_SZ);
        const u8* gAx = An + (size_t)(((remn >> 5) * 128) + (t >> 2)) * D_SZ + chunk * 16;
        const u8* gBx = Bn + (size_t)(((remn & 31) * 128) + (t >> 2)) * D_SZ + chunk * 16;

        #pragma unroll
        for (int si = 0; si < D_SZ / 64; ++si) {
            const int cur = si % 3;
            // own prior-step ds_reads consumed before the barrier (buffer-
            // reuse safety for the distance-2 DMA target); then wait ONLY
            // stage(si): in-flight = stage(si)+stage(si+1) = 4 -> vmcnt(2).
            asm volatile("s_waitcnt lgkmcnt(0)" ::: "memory");
            if (si < 7) { asm volatile("s_waitcnt vmcnt(2)" ::: "memory"); }
            else        { asm volatile("s_waitcnt vmcnt(0)" ::: "memory"); }
            asm volatile("s_barrier" ::: "memory");
            if (si < 6) {
                // prefetch distance 2: stage(si+2) into buf[(si+2)%3]
                // (= buf[(si-1)%3], fully read before barrier(si)).
                const int nxb = (si + 2) % 3;
                const int ko  = (si + 2) * 64;
                GLD_LDS16(gA + ko, &sA[nxb][wave * 1024]);
                GLD_LDS16(gB + ko, &sB[nxb][wave * 1024]);
            } else if (si == 7 && tile < 5) {
                // cross-tile: next tile's stage(0) into buf0 (last read at
                // si==6; all waves past barrier(7) -> safe).
                GLD_LDS16(gAx, &sA[0][wave * 1024]);
                GLD_LDS16(gBx, &sB[0][wave * 1024]);
            }
            const u8* pA = &sA[cur][0];
            const u8* pB = &sB[cur][0];
            lng2 a0 = *(const lng2*)(pA + aBase);
            lng2 a1 = *(const lng2*)(pA + aBase + 1024);
            lng2 b0 = *(const lng2*)(pB + bBase);
            lng2 b1 = *(const lng2*)(pB + bBase + 1024);
            lng2 b2 = *(const lng2*)(pB + bBase + 2048);
            lng2 b3 = *(const lng2*)(pB + bBase + 3072);
            FP8MFMA(acc[0][0], a0.x, b0.x); FP8MFMA(acc[0][1], a0.x, b1.x);
            FP8MFMA(acc[0][2], a0.x, b2.x); FP8MFMA(acc[0][3], a0.x, b3.x);
            FP8MFMA(acc[1][0], a1.x, b0.x); FP8MFMA(acc[1][1], a1.x, b1.x);
            FP8MFMA(acc[1][2], a1.x, b2.x); FP8MFMA(acc[1][3], a1.x, b3.x);
            FP8MFMA(acc[0][0], a0.y, b0.y); FP8MFMA(acc[0][1], a0.y, b1.y);
            FP8MFMA(acc[0][2], a0.y, b2.y); FP8MFMA(acc[0][3], a0.y, b3.y);
            FP8MFMA(acc[1][0], a1.y, b0.y); FP8MFMA(acc[1][1], a1.y, b1.y);
            FP8MFMA(acc[1][2], a1.y, b2.y); FP8MFMA(acc[1][3], a1.y, b3.y);
        }

        if (tile < 5) {
            // cross-tile: stage(1) into buf1 (read at si==7 by ALL waves ->
            // need my lgkm done + a barrier before the DMA).
            asm volatile("s_waitcnt lgkmcnt(0)" ::: "memory");
            asm volatile("s_barrier" ::: "memory");
            GLD_LDS16(gAx + 64, &sA[1][wave * 1024]);
            GLD_LDS16(gBx + 64, &sB[1][wave * 1024]);
        }

        // ---- slim fused epilogue (verified R7-R28, unchanged); runs with
        //      next tile's 4 staging loads in flight. ----
        const float* tA = times + pa * B_SZ;
        const float* tB = times + pb * B_SZ;
        int rowbase = rowBlk + wr * 32;
        int colbase = colBlk + wc * 64;

        float tb[4]; int lb[4]; int mcol[4];
        #pragma unroll
        for (int j = 0; j < 4; ++j) {
            mcol[j] = colbase + j * 16 + s;
            tb[j] = tB[mcol[j]];
            lb[j] = labels[mcol[j]];
        }
        float colE[4] = {0.f, 0.f, 0.f, 0.f}, colT[4] = {0.f, 0.f, 0.f, 0.f};

        float* rsE = rsum_e + z * B_SZ;
        float* rsT = rsum_t + z * B_SZ;
        float* csE = csum_e + z * B_SZ;
        float* csT = csum_t + z * B_SZ;

        #pragma unroll
        for (int ii = 0; ii < 2; ++ii) {
            int nb = rowbase + ii * 16 + q * 4;   // this lane's 4 C rows
            float cta[4]; int la[4];
            #pragma unroll
            for (int r = 0; r < 4; ++r) { cta[r] = curv * tA[nb + r]; la[r] = labels[nb + r]; }
            float re[4] = {0.f, 0.f, 0.f, 0.f}, rt[4] = {0.f, 0.f, 0.f, 0.f};
            #pragma unroll
            for (int j = 0; j < 4; ++j) {
                floatx4 a = acc[ii][j];
                #pragma unroll
                for (int r = 0; r < 4; ++r) {
                    float zc = fmaf(-curv, a[r], cta[r] * tb[j]);
                    zc = fmaxf(zc, 1.0f + 1e-8f);
                    float lz = __log2f(zc);
                    float e = __builtin_amdgcn_exp2f(fmaf(c2, lz, sh2p));
                    float tl2 = (la[r] == lb[j]) ? fmaf(c1, lz, c1) : 0.0f;
                    re[r] += e; rt[r] += tl2;
                    colE[j] += e; colT[j] += tl2;
                }
            }
            #pragma unroll
            for (int r = 0; r < 4; ++r) {
                #pragma unroll
                for (int m = 1; m <= 8; m <<= 1) {
                    re[r] += __shfl_xor(re[r], m);
                    rt[r] += __shfl_xor(rt[r], m);
                }
            }
            #pragma unroll
            for (int r = 0; r < 4; ++r) {
                if (s == r) {
                    atomicAdd(&rsE[nb + r], re[r]);
                    atomicAdd(&rsT[nb + r], rt[r]);
                }
            }
        }
        #pragma unroll
        for (int j = 0; j < 4; ++j) {
            colE[j] += __shfl_xor(colE[j], 16); colE[j] += __shfl_xor(colE[j], 32);
            colT[j] += __shfl_xor(colT[j], 16); colT[j] += __shfl_xor(colT[j], 32);
            if (q == 0) {
                atomicAdd(&csE[mcol[j]], colE[j]);
                atomicAdd(&csT[mcol[j]], colT[j]);
            }
        }
        // next tile's si=0: lgkmcnt(0) + vmcnt(2) + barrier resync.
    }
}

// ---- parallel finalize: 16 blocks, device-scope atomic accumulation; last
//      block (done counter) writes out. atomicAdd(p,0) read avoids stale L2. ----
__global__ __launch_bounds__(256) void finalize_kernel(
    const float* __restrict__ rsum_e, const float* __restrict__ rsum_t,
    const float* __restrict__ csum_e, const float* __restrict__ csum_t,
    const int* __restrict__ labels, const int* __restrict__ hist,
    const float* __restrict__ ent_partial,
    float* __restrict__ ce_acc, float* __restrict__ ent_acc,
    int* __restrict__ done, float* __restrict__ out) {
    __shared__ float red[4], red2[4];
    int b = blockIdx.x, tid = threadIdx.x;
    int n = b * 256 + tid;                 // covers 0..4095 exactly
    float Sn = (float)hist[labels[n]];
    float part = 0.0f;
    #pragma unroll
    for (int p = 0; p < 3; ++p) {
        part += Sn * (__logf(rsum_e[p * B_SZ + n]) - SHIFT) - rsum_t[p * B_SZ + n];
        part += Sn * (__logf(csum_e[p * B_SZ + n]) - SHIFT) - csum_t[p * B_SZ + n];
    }
    float ep = (b < 4) ? ent_partial[b * 256 + tid] : 0.0f;
    #pragma unroll
    for (int m = 1; m < 64; m <<= 1) {
        part += __shfl_xor(part, m);
        ep   += __shfl_xor(ep, m);
    }
    if ((tid & 63) == 0) { red[tid >> 6] = part; red2[tid >> 6] = ep; }
    __syncthreads();
    if (tid == 0) {
        atomicAdd(ce_acc, red[0] + red[1] + red[2] + red[3]);
        atomicAdd(ent_acc, red2[0] + red2[1] + red2[2] + red2[3]);
        __threadfence();
        if (atomicAdd(done, 1) == 15) {        // last of 16 blocks
            float ce = atomicAdd(ce_acc, 0.0f);    // coherent read
            float ent = atomicAdd(ent_acc, 0.0f);
            float contr = ce / (6.0f * (float)B_SZ);
            ent /= (float)B_SZ;
            out[0] = contr + 0.2f * ent;
            out[1] = contr;
            out[2] = ent;
        }
    }
}

// ---- workspace layout (bytes) ----
//   0       : fp8 feats (K-interleaved), 3*4096*512 = 6,291,456
//   6291456 : times[3][4096] f32   (49,152)
//   6340608 : rsum_e[12288 f]  \
//   6389760 : rsum_t           | zero region: 49155 floats
//   6438912 : csum_e           | (incl. ce_acc, ent_acc, done)
//   6488064 : csum_t           |
//   6537216 : ce_acc f32; 6537220: ent_acc f32; 6537224: done i32
//   6537228 : ent_partial[1024] f32 (every slot written by its dna block)
//   6541324 : hist[512] int (fully written by prep block 0)
extern "C" void kernel_launch(void* const* d_in, const int* in_sizes, int n_in,
                              void* d_out, int out_size, void* d_ws, size_t ws_size,
                              hipStream_t stream) {
    const float* img    = (const float*)d_in[0];
    const float* dna    = (const float*)d_in[1];
    const float* txt    = (const float*)d_in[2];
    const int*   labels = (const int*)d_in[3];
    const float* ls     = (const float*)d_in[4];
    const float* curv   = (const float*)d_in[5];

    char* ws = (char*)d_ws;
    u8*    f8     = (u8*)ws;
    float* times  = (float*)(ws + 6291456);
    float* rsum_e = (float*)(ws + 6340608);
    float* rsum_t = (float*)(ws + 6389760);
    float* csum_e = (float*)(ws + 6438912);
    float* csum_t = (float*)(ws + 6488064);
    float* ce_acc = (float*)(ws + 6537216);
    float* ent_acc= (float*)(ws + 6537220);
    int*   done   = (int*)  (ws + 6537224);
    float* ent_p  = (float*)(ws + 6537228);
    int*   hist   = (int*)  (ws + 6541324);

    prep_kernel<<<3072, 256, 0, stream>>>(img, dna, txt, curv, labels, hist,
                                          f8, times, rsum_e, ent_p);
    gemm_epi_kernel<<<512, 512, 0, stream>>>(f8, times, labels, ls, curv,
                                             rsum_e, rsum_t, csum_e, csum_t);
    finalize_kernel<<<16, 256, 0, stream>>>(rsum_e, rsum_t, csum_e, csum_t,
                                            labels, hist, ent_p,
                                            ce_acc, ent_acc, done, (float*)d_out);
}